// Round 7
// baseline (110.328 us; speedup 1.0000x reference)
//
#include <hip/hip_runtime.h>
#include <stdint.h>

#define NQ 14
#define STATE 16384
#define BATCH 512
#define THREADS 512
#define PER 32
#define STRIDE 132                 // full-map: 128 + 4 pad (16B-aligned, bank-rotating)
#define LDS_WORDS (128 * STRIDE)  // 16896 words = 67584 B (dynamic LDS, 2 blocks/CU)
#define STRIDE2 68                 // pair-word map: 64 + 4 pad
#define WSLICE 2112                // per-wave word slice (16*132); 2112%32==0 -> bank-neutral
#define SCALE 6.103515625e-05f    // 2^-14: both FWHT norms folded into the rotation

typedef float v2f __attribute__((ext_vector_type(2)));  // -> v_pk_*_f32

__device__ __forceinline__ int adr(int row, int col) { return row * STRIDE + col; }

// bf16-pair packing: one b32 word carries two floats (lo16 = v[0], hi16 = v[1]).
__device__ __forceinline__ uint32_t pk2(v2f v) {
    uint32_t rb = __float_as_uint(v[0]) + 0x8000u;
    uint32_t ib = __float_as_uint(v[1]) + 0x8000u;
    return (ib & 0xFFFF0000u) | (rb >> 16);
}
__device__ __forceinline__ v2f upk2(uint32_t w) {
    v2f v;
    v[0] = __uint_as_float(w << 16);
    v[1] = __uint_as_float(w & 0xFFFF0000u);
    return v;
}

// Packed FWHT over index bits m=1..MAXM of a v2f array.
template <int MAXM, int N>
__device__ __forceinline__ void fwht_q(v2f (&x)[N]) {
#pragma unroll
    for (int m = 1; m <= MAXM; m <<= 1) {
#pragma unroll
        for (int r = 0; r < N; ++r) {
            if (!(r & m)) {
                v2f a = x[r], b = x[r | m];
                x[r] = a + b;
                x[r | m] = a - b;
            }
        }
    }
}
// Cross-pair butterfly: {a,b} -> {a+b, a-b} (the packed dimension's own stage).
template <int N>
__device__ __forceinline__ void fwht_cross(v2f (&x)[N]) {
#pragma unroll
    for (int r = 0; r < N; ++r) {
        float a = x[r][0], b = x[r][1];
        x[r] = v2f{a + b, a - b};
    }
}

// Maps (word index = complex elem in t1, real pair in t2's XCHG3):
// L0: s = (r>>2)*2048 + t*4 + (r&3)   reg bits s{0,1,11,12,13}; rows cross-wave
// L1: s = (t>>2)*128 + r*4 + (t&3)    reg bits s{2..6} (bit4 of r = s6); rows wave-local
// L2: s = (t>>6)*2048 + (r&15)*128 + (r>>4)*64 + ((t>>2)&15)*4 + (t&3)
//     reg bits s{7..10}, bit4 of r = s6; rows wave-local
// Pair-word map (XCHG3): word = (s, s+64), addr = WSLICE*w + j*STRIDE2 + col.

__global__ void __launch_bounds__(THREADS, 4)
rx_kernel(const float* __restrict__ phr, const float* __restrict__ phim,
          const float* __restrict__ th, float* __restrict__ out,
          long long out_limit) {
    extern __shared__ float lds[];   // 67584 B -> 2 blocks/CU
    uint32_t* ldsw = (uint32_t*)lds;
    const int b = blockIdx.x;
    const int t = threadIdx.x;
    v2f x[PER];                      // t1: complex (re, im)

    const float* pr = phr + (size_t)b * STATE;
    const float* pi = phim + (size_t)b * STATE;

    // ---- load, chunk-interleaved with the s{0,1} butterflies ----
#pragma unroll
    for (int i = 0; i < 8; ++i) {
        float4 a = *(const float4*)(pr + i * 2048 + t * 4);
        float4 c = *(const float4*)(pi + i * 2048 + t * 4);
        v2f e0{a.x, c.x}, e1{a.y, c.y}, e2{a.z, c.z}, e3{a.w, c.w};
        // m=1 (s0), m=2 (s1) within this chunk:
        v2f s01 = e0 + e1, d01 = e0 - e1, s23 = e2 + e3, d23 = e2 - e3;
        x[4 * i]     = s01 + s23;
        x[4 * i + 1] = d01 + d23;
        x[4 * i + 2] = s01 - s23;
        x[4 * i + 3] = d01 - d23;
    }
    float w[NQ];   // w[k] multiplies bit k (LSB) of s: w[k] = theta[13-k]
#pragma unroll
    for (int k = 0; k < NQ; ++k) w[k] = th[b * NQ + 13 - k];

    // ---- remaining L0 bits (s11,s12,s13 = r bits 2,3,4): m=4,8,16 ----
#pragma unroll
    for (int m = 4; m <= 16; m <<= 1) {
#pragma unroll
        for (int r = 0; r < PER; ++r) {
            if (!(r & m)) {
                v2f a2 = x[r], b2 = x[r | m];
                x[r] = a2 + b2;
                x[r | m] = a2 - b2;
            }
        }
    }

    // XCHG1 (L0 -> L1): one pass, complex as bf16-pair words. 1 barrier.
    {
#pragma unroll
        for (int i = 0; i < 8; ++i) {
            uint4 v = make_uint4(pk2(x[4 * i]), pk2(x[4 * i + 1]),
                                 pk2(x[4 * i + 2]), pk2(x[4 * i + 3]));
            *(uint4*)&ldsw[adr(i * 16 + (t >> 5), (t & 31) * 4)] = v;  // b128
        }
        __syncthreads();                                               // S1
        const int base = adr(t >> 2, t & 3);
#pragma unroll
        for (int r = 0; r < PER; ++r) x[r] = upk2(ldsw[base + r * 4]); // read2-merged
    }

    // ---- L1 bits {2..6} ----
    fwht_q<16, PER>(x);

    // XCHG2 (L1 -> L2): wave-local both sides -> NO barrier; packed complex words.
    {
        const int base = adr(t >> 2, t & 3);
#pragma unroll
        for (int r = 0; r < PER; ++r) ldsw[base + r * 4] = pk2(x[r]);  // write2-merged
        const int base2 = adr((t >> 6) * 16, ((t >> 2) & 15) * 4 + (t & 3));
#pragma unroll
        for (int r = 0; r < PER; ++r)
            x[r] = upk2(ldsw[base2 + (r & 15) * STRIDE + (r >> 4) * 64]);
    }

    // ---- L2 bits {7..10} ----
    fwht_q<8, PER>(x);

    // ---- rotation; output = REAL part only, so im dies here ----
    // q[j] = { real(s6=0 elem), real(s6=1 elem) }, j = s{7..10} bits.
    float tp = 0.f;
    if (t & 1)   tp += w[0];
    if (t & 2)   tp += w[1];
    if (t & 4)   tp += w[2];
    if (t & 8)   tp += w[3];
    if (t & 16)  tp += w[4];
    if (t & 32)  tp += w[5];
    if (t & 64)  tp += w[11];
    if (t & 128) tp += w[12];
    if (t & 256) tp += w[13];
    v2f q[16];
#pragma unroll
    for (int j = 0; j < 16; ++j) {
        float ph = tp;
        if (j & 1) ph += w[7];
        if (j & 2) ph += w[8];
        if (j & 4) ph += w[9];
        if (j & 8) ph += w[10];
        const float a0 = -0.5f * ph;
        const float a1 = -0.5f * (ph + w[6]);
        const float lo = (x[j][0] * __cosf(a0) - x[j][1] * __sinf(a0)) * SCALE;
        const float hi = (x[j + 16][0] * __cosf(a1) - x[j + 16][1] * __sinf(a1)) * SCALE;
        q[j] = v2f{lo, hi};
    }

    // ---- transform 2, packed two-wide (pair dimension = s6, later s13) ----
    fwht_q<8, 16>(q);      // bits s{7..10}

    // XCHG3 (L2 -> L1): bf16 pair-words, wave-local, NO barrier.
    // write: word (s,s+64) at WSLICE*w + j*STRIDE2 + col; banks = col+lane: free.
    {
        const int wv = t >> 6;
        const int wbase = wv * WSLICE;
        const int wcol = ((t >> 2) & 15) * 4 + (t & 3);
#pragma unroll
        for (int j = 0; j < 16; ++j)
            ldsw[wbase + j * STRIDE2 + wcol] = pk2(q[j]);
        const int rbase = wbase + ((t >> 2) & 15) * STRIDE2 + (t & 3);
#pragma unroll
        for (int j = 0; j < 16; ++j)
            q[j] = upk2(ldsw[rbase + j * 4]);                          // read2-merged
    }

    // ---- L1 bits: s6 (cross-pair) + s{2..5} (packed) ----
    fwht_cross<16>(q);
    fwht_q<8, 16>(q);

    // XCHG4 (L1 -> L0): unpack to fp32 full map (pairing incompatible across it),
    // wave-local writes, 1 barrier, cross-wave b128 reads.
    float p[PER];
    {
        const int base = adr(t >> 2, t & 3);
#pragma unroll
        for (int j = 0; j < 16; ++j) lds[base + j * 4] = q[j][0];        // r = j
#pragma unroll
        for (int j = 0; j < 16; ++j) lds[base + (j + 16) * 4] = q[j][1]; // r = j+16
        __syncthreads();                                                 // S2
#pragma unroll
        for (int i = 0; i < 8; ++i) {
            float4 v = *(const float4*)&lds[adr(i * 16 + (t >> 5), (t & 31) * 4)];
            p[4 * i] = v.x; p[4 * i + 1] = v.y; p[4 * i + 2] = v.z; p[4 * i + 3] = v.w;
        }
    }

    // ---- final L0 block, packed: pair dimension = s13 (r bit 4) ----
    v2f q2[16];
#pragma unroll
    for (int j = 0; j < 16; ++j) q2[j] = v2f{p[j], p[j + 16]};
    fwht_q<8, 16>(q2);     // bits s0,s1 (m=1,2) + s11,s12 (m=4,8)
    fwht_cross<16>(q2);    // s13

    // ---- store real part, (512,16384) row-major, guarded ----
    float* o = out + (size_t)b * STATE;
    const long long obase = (long long)b * STATE;
#pragma unroll
    for (int i = 0; i < 8; ++i) {
        const int s0 = i * 2048 + t * 4;
        const int c = i >> 2, j0 = (i & 3) * 4;
        if (obase + s0 + 3 < out_limit)
            *(float4*)(o + s0) = make_float4(q2[j0][c], q2[j0 + 1][c],
                                             q2[j0 + 2][c], q2[j0 + 3][c]);
    }
}

extern "C" void kernel_launch(void* const* d_in, const int* in_sizes, int n_in,
                              void* d_out, int out_size, void* d_ws, size_t ws_size,
                              hipStream_t stream) {
    const float* phr  = (const float*)d_in[0];
    const float* phim = (const float*)d_in[1];
    const float* th   = (const float*)d_in[2];
    float* out = (float*)d_out;
    (void)hipFuncSetAttribute((const void*)rx_kernel,
                              hipFuncAttributeMaxDynamicSharedMemorySize,
                              LDS_WORDS * (int)sizeof(float));
    rx_kernel<<<BATCH, THREADS, LDS_WORDS * sizeof(float), stream>>>(
        phr, phim, th, out, (long long)out_size);
}